// Round 1
// baseline (43810.556 us; speedup 1.0000x reference)
//
#include <hip/hip_runtime.h>
#include <stdint.h>

#define B_ 64
#define T_ 512
#define I_ 256
#define H_ 512
#define G0_ 128
#define G1_ 128
#define NTHR_ 512
#define D_ 8   // ring depth (power of 2)

typedef __attribute__((ext_vector_type(8))) short short8;
typedef __attribute__((ext_vector_type(4))) float float4v;

static_assert(sizeof(short8) == 16, "");

// ---- bf16 helpers (round-to-nearest-even) ----
__device__ __forceinline__ unsigned short f2bf(float x) {
  union { float f; uint32_t u; } v; v.f = x;
  uint32_t r = v.u + 0x7FFFu + ((v.u >> 16) & 1u);
  return (unsigned short)(r >> 16);
}
__device__ __forceinline__ float bf2f(unsigned short h) {
  union { uint32_t u; float f; } v; v.u = ((uint32_t)h) << 16; return v.f;
}
__device__ __forceinline__ void splitHL(float x, unsigned short& hi, unsigned short& lo) {
  hi = f2bf(x);
  lo = f2bf(x - bf2f(hi));   // x - hi is exact in fp32
}

// ring element offset (ushort units). layout: [slot][bg][ktile][lane][j]
__device__ __forceinline__ size_t roff(int slot, int bg, int ht, int lane) {
  return ((size_t)((slot * 4 + bg) * 16 + ht)) * 512 + (size_t)lane * 8;
}

__device__ __forceinline__ void wait_eq(const uint32_t* c, int idx, uint32_t tgt) {
  if (idx < 0) return;
  int it = 0;
  while (__hip_atomic_load(&c[idx], __ATOMIC_RELAXED, __HIP_MEMORY_SCOPE_AGENT) < tgt) {
    __builtin_amdgcn_s_sleep(2);
    if (++it > 5000000) break;   // safety: degrade to wrong answer, never hang
  }
}

#define MFMA16(A, Bv, C) __builtin_amdgcn_mfma_f32_16x16x32_bf16(A, Bv, C, 0, 0, 0)

// One LSTM layer, persistent across all T steps.
// Block 'a' owns h-columns [4a, 4a+4) -> 16 gate columns (4 gates x 4 cols).
// Gate-col cc = g*4 + d, n = 4a+d.  K space: [0,K1)=inp (x or h0), [K1,K1+512)=h_rec.
// MFMA frag conventions (self-consistent K bijection):
//   k(q,j) = 4q + (j&3) + 16*(j>>2), q = lane>>4
//   A: row m = lane&15 (batch within group), B: col = lane&15 (gate col)
//   C/D: col = lane&15, row = 4*(lane>>4) + i   (m89-verified)
template <int LAYER>
__device__ void run_layer(
    int a,
    const float* __restrict__ x,
    const float* __restrict__ Wxp, const float* __restrict__ bxp,
    const float* __restrict__ Whp,
    uint32_t* cnt0, uint32_t* cnt1,
    unsigned short* h0hi, unsigned short* h0lo,
    unsigned short* h1hi, unsigned short* h1lo,
    float* h1f,
    unsigned short* Wsh, float* red)
{
  constexpr int K1 = LAYER ? H_ : I_;
  constexpr int NT = (K1 + H_) / 32;   // 24 (L0) or 32 (L1) K-tiles
  constexpr int NTT = NT / 2;          // tiles per k-half wavegroup
  const int tid = threadIdx.x;
  const int lane = tid & 63;
  const int wid = tid >> 6;     // 0..7
  const int bg = wid & 3;       // batch group (16 batches)
  const int kh = wid >> 2;      // K-half (parity of tile)
  const int qq = lane >> 4;
  const int cc = lane & 15;     // gate column within block

  // ---- stage weight slice: pass0 = LO (pulled to regs), pass1 = HI (stays in LDS) ----
  short8 wlo[NTT];
  for (int pass = 0; pass < 2; ++pass) {
    for (int idx = tid; idx < NT * 512; idx += NTHR_) {
      int tile = idx >> 9, r = idx & 511, ln = r >> 3, j = r & 7;
      int k = tile * 32 + 4 * (ln >> 4) + (j & 3) + 16 * (j >> 2);
      int n = 4 * a + (ln & 3);
      int g = (ln & 15) >> 2;
      float wvv = (k < K1) ? Wxp[((size_t)g * K1 + k) * H_ + n]
                           : Whp[((size_t)g * H_ + (k - K1)) * H_ + n];
      unsigned short hi, lo; splitHL(wvv, hi, lo);
      Wsh[idx] = pass ? hi : lo;
    }
    __syncthreads();
    if (pass == 0) {
      #pragma unroll
      for (int tt = 0; tt < NTT; ++tt) {
        int tile = 2 * tt + kh;
        wlo[tt] = *(const short8*)(Wsh + tile * 512 + lane * 8);
      }
      __syncthreads();   // all pulled before HI overwrites
    }
  }

  const float biasv = bxp[(size_t)(cc >> 2) * H_ + 4 * a + (cc & 3)];
  float cst[4] = {0.f, 0.f, 0.f, 0.f};   // private cell state (rows 4qq+i, col n=4a+cc; valid cc<4)

  uint32_t* mycnt = LAYER ? cnt1 : cnt0;

  for (int t = 0; t < T_; ++t) {
    // ---- wait: read-ready + ring backpressure (all refer to strictly earlier steps) ----
    if (tid == 0) {
      if (!LAYER) {
        wait_eq(cnt0, t - 1, G0_);                                  // h0[t-1] ready
        if (t >= D_) { wait_eq(cnt0, t - D_ + 1, G0_); wait_eq(cnt1, t - D_, G1_); }
      } else {
        wait_eq(cnt1, t - 1, G1_);                                  // h1[t-1] ready
        if (t >= D_) wait_eq(cnt1, t - D_ + 1, G1_);
        wait_eq(cnt0, t, G0_);                                      // h0[t] ready
      }
    }
    __syncthreads();
    __threadfence();   // acquire: invalidate stale cached ring lines

    const int sp = (t - 1) & (D_ - 1);
    const int sc = t & (D_ - 1);
    float bv = (kh == 0) ? biasv : 0.f;
    float4v acc = {bv, bv, bv, bv};

    #pragma unroll
    for (int tt = 0; tt < NTT; ++tt) {
      const int tile = 2 * tt + kh;
      short8 ahi, alo;
      if (!LAYER && tt < 4) {
        // x fragment built on the fly from fp32
        const float* xp = x + ((size_t)(bg * 16 + (lane & 15)) * T_ + t) * I_
                            + tile * 32 + 4 * qq;
        float4v f0 = *(const float4v*)xp;
        float4v f1 = *(const float4v*)(xp + 16);
        #pragma unroll
        for (int j = 0; j < 4; ++j) {
          unsigned short hh, ll;
          splitHL(f0[j], hh, ll); ahi[j] = (short)hh; alo[j] = (short)ll;
          splitHL(f1[j], hh, ll); ahi[j + 4] = (short)hh; alo[j + 4] = (short)ll;
        }
      } else {
        const unsigned short *ph, *pl; size_t off;
        if (!LAYER)      { off = roff(sp, bg, tile - 8, lane);  ph = h0hi; pl = h0lo; }
        else if (tt < 8) { off = roff(sc, bg, tile, lane);      ph = h0hi; pl = h0lo; }
        else             { off = roff(sp, bg, tile - 16, lane); ph = h1hi; pl = h1lo; }
        ahi = *(const short8*)(ph + off);
        alo = *(const short8*)(pl + off);
      }
      short8 bhi = *(const short8*)(Wsh + tile * 512 + lane * 8);
      acc = MFMA16(ahi, bhi, acc);       // hi*hi
      acc = MFMA16(alo, bhi, acc);       // lo*hi
      acc = MFMA16(ahi, wlo[tt], acc);   // hi*lo
    }

    // ---- split-K reduction through LDS ----
    if (kh == 1) *(float4v*)(red + ((bg << 6) + lane) * 4) = acc;
    __syncthreads();
    if (kh == 0) {
      acc += *(const float4v*)(red + ((bg << 6) + lane) * 4);

      // activations: cols 0-11 sigmoid (i,f,o), 12-15 tanh (g)
      const bool isg = cc >= 12;
      float av[4];
      #pragma unroll
      for (int i = 0; i < 4; ++i) {
        float xg = acc[i];
        float arg = isg ? xg + xg : xg;
        float e = __expf(-fabsf(arg));
        float s = (arg >= 0.f) ? 1.f / (1.f + e) : e / (1.f + e);
        av[i] = isg ? (s + s - 1.f) : s;   // tanh(x) = 2*sigmoid(2x)-1
      }
      float hn[4];
      #pragma unroll
      for (int i = 0; i < 4; ++i) {
        float fv = __shfl_xor(av[i], 4);
        float ov = __shfl_xor(av[i], 8);
        float gv = __shfl_xor(av[i], 12);
        float cn = fv * cst[i] + av[i] * gv;
        cst[i] = cn;
        float e2 = __expf(-2.f * fabsf(cn));
        float th = (1.f - e2) / (1.f + e2);
        hn[i] = ov * ((cn >= 0.f) ? th : -th);
      }
      if (cc < 4) {   // lanes holding the i-gate column own the (b, n=4a+cc) update
        unsigned short* dh = LAYER ? h1hi : h0hi;
        unsigned short* dl = LAYER ? h1lo : h0lo;
        size_t base = roff(sc, bg, a >> 3, 16 * (a & 3) + 4 * qq)
                      + (size_t)(cc + 4 * ((a >> 2) & 1));
        #pragma unroll
        for (int i = 0; i < 4; ++i) {
          unsigned short hh, ll; splitHL(hn[i], hh, ll);
          dh[base + (size_t)i * 8] = hh;
          dl[base + (size_t)i * 8] = ll;
        }
        if (LAYER && t == T_ - 1) {
          #pragma unroll
          for (int i = 0; i < 4; ++i)
            h1f[(size_t)(bg * 16 + 4 * qq + i) * H_ + 4 * a + cc] = hn[i];
        }
      }
    }
    __threadfence();   // release: push ring writes to device scope
    __syncthreads();
    if (tid == 0)
      __hip_atomic_fetch_add(&mycnt[t], 1u, __ATOMIC_RELEASE, __HIP_MEMORY_SCOPE_AGENT);
  }
}

__global__ __launch_bounds__(NTHR_, 2) void lstm_persist(
    const float* __restrict__ x,
    const float* __restrict__ Wx0, const float* __restrict__ bx0, const float* __restrict__ Wh0,
    const float* __restrict__ Wx1, const float* __restrict__ bx1, const float* __restrict__ Wh1,
    uint32_t* cnt0, uint32_t* cnt1,
    unsigned short* h0hi, unsigned short* h0lo,
    unsigned short* h1hi, unsigned short* h1lo,
    float* h1f)
{
  __shared__ unsigned short Wsh[16384];  // 32 KB: W-hi frags
  __shared__ float red[1024];            // 4 KB: split-K reduction
  if (blockIdx.x < G0_)
    run_layer<0>(blockIdx.x, x, Wx0, bx0, Wh0, cnt0, cnt1, h0hi, h0lo, h1hi, h1lo, h1f, Wsh, red);
  else
    run_layer<1>(blockIdx.x - G0_, x, Wx1, bx1, Wh1, cnt0, cnt1, h0hi, h0lo, h1hi, h1lo, h1f, Wsh, red);
}

__global__ void fc_out(const float* __restrict__ h1f, const float* __restrict__ Wfc,
                       const float* __restrict__ bfc, float* __restrict__ out)
{
  int tid = threadIdx.x;     // 512 threads: 64 batches x 8 partials
  int b = tid >> 3, p = tid & 7;
  float s = 0.f;
  const float* hp = h1f + (size_t)b * H_ + p * 64;
  const float* wp = Wfc + p * 64;
  #pragma unroll 16
  for (int n = 0; n < 64; ++n) s += hp[n] * wp[n];
  s += __shfl_xor(s, 1);
  s += __shfl_xor(s, 2);
  s += __shfl_xor(s, 4);
  if (p == 0) out[b] = s + bfc[0];
}

extern "C" void kernel_launch(void* const* d_in, const int* in_sizes, int n_in,
                              void* d_out, int out_size, void* d_ws, size_t ws_size,
                              hipStream_t stream)
{
  const float* x   = (const float*)d_in[0];
  const float* Wx0 = (const float*)d_in[1];
  const float* bx0 = (const float*)d_in[2];
  const float* Wh0 = (const float*)d_in[3];
  const float* Wx1 = (const float*)d_in[4];
  const float* bx1 = (const float*)d_in[5];
  const float* Wh1 = (const float*)d_in[6];
  const float* Wfc = (const float*)d_in[7];
  const float* bfc = (const float*)d_in[8];

  uint8_t* ws = (uint8_t*)d_ws;
  uint32_t* cnt0 = (uint32_t*)ws;                 // [512]
  uint32_t* cnt1 = (uint32_t*)(ws + 2048);        // [512]
  const size_t RING = (size_t)D_ * 4 * 16 * 512 * sizeof(unsigned short);  // 512 KB
  unsigned short* h0hi = (unsigned short*)(ws + 8192);
  unsigned short* h0lo = (unsigned short*)(ws + 8192 + RING);
  unsigned short* h1hi = (unsigned short*)(ws + 8192 + 2 * RING);
  unsigned short* h1lo = (unsigned short*)(ws + 8192 + 3 * RING);
  float* h1f = (float*)(ws + 8192 + 4 * RING);    // 128 KB, fully rewritten each call

  // counters + rings must be zero every call (slot D-1 is the t=-1 state)
  (void)hipMemsetAsync(ws, 0, 8192 + 4 * RING, stream);

  hipLaunchKernelGGL(lstm_persist, dim3(G0_ + G1_), dim3(NTHR_), 0, stream,
                     x, Wx0, bx0, Wh0, Wx1, bx1, Wh1,
                     cnt0, cnt1, h0hi, h0lo, h1hi, h1lo, h1f);
  hipLaunchKernelGGL(fc_out, dim3(1), dim3(512), 0, stream,
                     h1f, Wfc, bfc, (float*)d_out);
}

// Round 2
// 7231.104 us; speedup vs baseline: 6.0586x; 6.0586x over previous
//
#include <hip/hip_runtime.h>
#include <stdint.h>

#define B_ 64
#define T_ 512
#define I_ 256
#define H_ 512
#define G0_ 128
#define G1_ 128
#define NTHR_ 512
#define D_ 8   // ring depth (power of 2)

typedef __attribute__((ext_vector_type(8))) short short8;
typedef __attribute__((ext_vector_type(4))) float float4v;

static_assert(sizeof(short8) == 16, "");

// ---- bf16 helpers (round-to-nearest-even) ----
__device__ __forceinline__ unsigned short f2bf(float x) {
  union { float f; uint32_t u; } v; v.f = x;
  uint32_t r = v.u + 0x7FFFu + ((v.u >> 16) & 1u);
  return (unsigned short)(r >> 16);
}
__device__ __forceinline__ float bf2f(unsigned short h) {
  union { uint32_t u; float f; } v; v.u = ((uint32_t)h) << 16; return v.f;
}
__device__ __forceinline__ void splitHL(float x, unsigned short& hi, unsigned short& lo) {
  hi = f2bf(x);
  lo = f2bf(x - bf2f(hi));   // x - hi is exact in fp32
}

// ring element offset (u32 units). layout: [slot][bg][ktile][lane][j], j=0..7 packed u32
__device__ __forceinline__ size_t roff(int slot, int bg, int ht, int lane) {
  return ((size_t)((slot * 4 + bg) * 16 + ht)) * 512 + (size_t)lane * 8;
}

// per-thread spin on a single progress word (cache-bypass load, no fences)
__device__ __forceinline__ void wait_ge(const uint32_t* p, int tgt) {
  if (tgt <= 0) return;
  int it = 0;
  while ((int)__hip_atomic_load(p, __ATOMIC_RELAXED, __HIP_MEMORY_SCOPE_AGENT) < tgt) {
    if (++it > 1000000) break;   // safety: degrade to wrong answer, never hang
  }
}

// read one 16B hi-frag + 16B lo-frag as 4x u64 coherent (bypass) loads + unpack
__device__ __forceinline__ void ring_read(const uint32_t* p, short8& hi, short8& lo) {
  #pragma unroll
  for (int q = 0; q < 4; ++q) {
    unsigned long long w = __hip_atomic_load(
        (const unsigned long long*)p + q, __ATOMIC_RELAXED, __HIP_MEMORY_SCOPE_AGENT);
    uint32_t w0 = (uint32_t)w, w1 = (uint32_t)(w >> 32);
    hi[2 * q]     = (short)(w0 >> 16); lo[2 * q]     = (short)(w0 & 0xffffu);
    hi[2 * q + 1] = (short)(w1 >> 16); lo[2 * q + 1] = (short)(w1 & 0xffffu);
  }
}

#define MFMA16(A, Bv, C) __builtin_amdgcn_mfma_f32_16x16x32_bf16(A, Bv, C, 0, 0, 0)

// One LSTM layer, persistent across all T steps.
// Block 'a' owns h-columns [4a, 4a+4) -> 16 gate columns (4 gates x 4 cols).
// K space: [0,K1)=inp (x or h0), [K1,K1+512)=h_rec.
// MFMA frag conventions (self-consistent K bijection):
//   k(q,j) = 4q + (j&3) + 16*(j>>2), q = lane>>4
//   A: row m = lane&15, B: col = lane&15
//   C/D: col = lane&15, row = 4*(lane>>4) + i   (m89-verified)
template <int LAYER>
__device__ void run_layer(
    int a,
    const float* __restrict__ x,
    const float* __restrict__ Wxp, const float* __restrict__ bxp,
    const float* __restrict__ Whp,
    uint32_t* prog0, uint32_t* prog1,
    uint32_t* ring0, uint32_t* ring1,
    float* h1f,
    unsigned short* Wsh, float* red)
{
  constexpr int K1 = LAYER ? H_ : I_;
  constexpr int NT = (K1 + H_) / 32;   // 24 (L0) or 32 (L1) K-tiles
  constexpr int NTT = NT / 2;          // tiles per k-half wavegroup
  const int tid = threadIdx.x;
  const int lane = tid & 63;
  const int wid = tid >> 6;     // 0..7
  const int bg = wid & 3;       // batch group (16 batches)
  const int kh = wid >> 2;      // K-half (parity of tile)
  const int qq = lane >> 4;
  const int cc = lane & 15;     // gate column within block

  // ---- stage weight slice: pass0 = LO (pulled to regs), pass1 = HI (stays in LDS) ----
  short8 wlo[NTT];
  for (int pass = 0; pass < 2; ++pass) {
    for (int idx = tid; idx < NT * 512; idx += NTHR_) {
      int tile = idx >> 9, r = idx & 511, ln = r >> 3, j = r & 7;
      int k = tile * 32 + 4 * (ln >> 4) + (j & 3) + 16 * (j >> 2);
      int n = 4 * a + (ln & 3);
      int g = (ln & 15) >> 2;
      float wvv = (k < K1) ? Wxp[((size_t)g * K1 + k) * H_ + n]
                           : Whp[((size_t)g * H_ + (k - K1)) * H_ + n];
      unsigned short hi, lo; splitHL(wvv, hi, lo);
      Wsh[idx] = pass ? hi : lo;
    }
    __syncthreads();
    if (pass == 0) {
      #pragma unroll
      for (int tt = 0; tt < NTT; ++tt) {
        int tile = 2 * tt + kh;
        wlo[tt] = *(const short8*)(Wsh + tile * 512 + lane * 8);
      }
      __syncthreads();   // all pulled before HI overwrites
    }
  }

  const float biasv = bxp[(size_t)(cc >> 2) * H_ + 4 * a + (cc & 3)];
  float cst[4] = {0.f, 0.f, 0.f, 0.f};

  uint32_t* myprog = LAYER ? prog1 : prog0;

  for (int t = 0; t < T_; ++t) {
    // ---- wait: read-ready + ring backpressure, per-block flags, zero contention ----
    // L0@t: prog0[*]>=t (h0[t-1] ready), prog1[*]>=t-7 (L1 consumed h0[t-8])
    // L1@t: prog0[*]>=t+1 (h0[t] ready), prog1[*]>=t (h1[t-1] ready; implies backpressure)
    const int tgt0 = LAYER ? (t + 1) : t;
    const int tgt1 = LAYER ? t : (t - (D_ - 1));
    if (tid < 128)      wait_ge(&prog0[tid], tgt0);
    else if (tid < 256) wait_ge(&prog1[tid - 128], tgt1);
    __syncthreads();

    const int sp = (t - 1) & (D_ - 1);
    const int sc = t & (D_ - 1);
    float bv = (kh == 0) ? biasv : 0.f;
    float4v acc = {bv, bv, bv, bv};

    #pragma unroll
    for (int tt = 0; tt < NTT; ++tt) {
      const int tile = 2 * tt + kh;
      short8 ahi, alo;
      if (!LAYER && tt < 4) {
        // x fragment built on the fly from fp32 (plain cached loads: x is read-only)
        const float* xp = x + ((size_t)(bg * 16 + (lane & 15)) * T_ + t) * I_
                            + tile * 32 + 4 * qq;
        float4v f0 = *(const float4v*)xp;
        float4v f1 = *(const float4v*)(xp + 16);
        #pragma unroll
        for (int j = 0; j < 4; ++j) {
          unsigned short hh, ll;
          splitHL(f0[j], hh, ll); ahi[j] = (short)hh; alo[j] = (short)ll;
          splitHL(f1[j], hh, ll); ahi[j + 4] = (short)hh; alo[j + 4] = (short)ll;
        }
      } else {
        const uint32_t* rp;
        if (!LAYER)      rp = ring0 + roff(sp, bg, tile - 8, lane);
        else if (tt < 8) rp = ring0 + roff(sc, bg, tile, lane);
        else             rp = ring1 + roff(sp, bg, tile - 16, lane);
        ring_read(rp, ahi, alo);
      }
      short8 bhi = *(const short8*)(Wsh + tile * 512 + lane * 8);
      acc = MFMA16(ahi, bhi, acc);       // hi*hi
      acc = MFMA16(alo, bhi, acc);       // lo*hi
      acc = MFMA16(ahi, wlo[tt], acc);   // hi*lo
    }

    // ---- split-K reduction through LDS ----
    if (kh == 1) *(float4v*)(red + ((bg << 6) + lane) * 4) = acc;
    __syncthreads();
    if (kh == 0) {
      acc += *(const float4v*)(red + ((bg << 6) + lane) * 4);

      // activations: cols 0-11 sigmoid (i,f,o), 12-15 tanh (g)
      const bool isg = cc >= 12;
      float av[4];
      #pragma unroll
      for (int i = 0; i < 4; ++i) {
        float xg = acc[i];
        float arg = isg ? xg + xg : xg;
        float e = __expf(-fabsf(arg));
        float s = (arg >= 0.f) ? 1.f / (1.f + e) : e / (1.f + e);
        av[i] = isg ? (s + s - 1.f) : s;   // tanh(x) = 2*sigmoid(2x)-1
      }
      float hn[4];
      #pragma unroll
      for (int i = 0; i < 4; ++i) {
        float fv = __shfl_xor(av[i], 4);
        float ov = __shfl_xor(av[i], 8);
        float gv = __shfl_xor(av[i], 12);
        float cn = fv * cst[i] + av[i] * gv;
        cst[i] = cn;
        float e2 = __expf(-2.f * fabsf(cn));
        float th = (1.f - e2) / (1.f + e2);
        hn[i] = ov * ((cn >= 0.f) ? th : -th);
      }
      if (cc < 4) {   // lanes holding the i-gate column own the (b, n=4a+cc) update
        uint32_t* dr = LAYER ? ring1 : ring0;
        size_t base = roff(sc, bg, a >> 3, 16 * (a & 3) + 4 * qq)
                      + (size_t)(cc + 4 * ((a >> 2) & 1));
        #pragma unroll
        for (int i = 0; i < 4; ++i) {
          unsigned short hh, ll; splitHL(hn[i], hh, ll);
          __hip_atomic_store(&dr[base + (size_t)i * 8],
                             ((uint32_t)hh << 16) | (uint32_t)ll,
                             __ATOMIC_RELAXED, __HIP_MEMORY_SCOPE_AGENT);
        }
        if (LAYER && t == T_ - 1) {
          #pragma unroll
          for (int i = 0; i < 4; ++i)
            h1f[(size_t)(bg * 16 + 4 * qq + i) * H_ + 4 * a + cc] = hn[i];
        }
      }
    }
    // drain this wave's ring stores, then block-wide barrier (compiler drains
    // every wave's vmcnt before s_barrier), then publish progress. No cache
    // maintenance ops anywhere: ring traffic is all sc0/sc1 write-through.
    asm volatile("s_waitcnt vmcnt(0)" ::: "memory");
    __syncthreads();
    if (tid == 0)
      __hip_atomic_store(&myprog[a], (uint32_t)(t + 1),
                         __ATOMIC_RELAXED, __HIP_MEMORY_SCOPE_AGENT);
  }
}

__global__ __launch_bounds__(NTHR_, 2) void lstm_persist(
    const float* __restrict__ x,
    const float* __restrict__ Wx0, const float* __restrict__ bx0, const float* __restrict__ Wh0,
    const float* __restrict__ Wx1, const float* __restrict__ bx1, const float* __restrict__ Wh1,
    uint32_t* prog0, uint32_t* prog1,
    uint32_t* ring0, uint32_t* ring1,
    float* h1f)
{
  __shared__ unsigned short Wsh[16384];  // 32 KB: W-hi frags
  __shared__ float red[1024];            // 4 KB: split-K reduction
  if (blockIdx.x < G0_)
    run_layer<0>(blockIdx.x, x, Wx0, bx0, Wh0, prog0, prog1, ring0, ring1, h1f, Wsh, red);
  else
    run_layer<1>(blockIdx.x - G0_, x, Wx1, bx1, Wh1, prog0, prog1, ring0, ring1, h1f, Wsh, red);
}

__global__ void fc_out(const float* __restrict__ h1f, const float* __restrict__ Wfc,
                       const float* __restrict__ bfc, float* __restrict__ out)
{
  int tid = threadIdx.x;     // 512 threads: 64 batches x 8 partials
  int b = tid >> 3, p = tid & 7;
  float s = 0.f;
  const float* hp = h1f + (size_t)b * H_ + p * 64;
  const float* wp = Wfc + p * 64;
  #pragma unroll 16
  for (int n = 0; n < 64; ++n) s += hp[n] * wp[n];
  s += __shfl_xor(s, 1);
  s += __shfl_xor(s, 2);
  s += __shfl_xor(s, 4);
  if (p == 0) out[b] = s + bfc[0];
}

extern "C" void kernel_launch(void* const* d_in, const int* in_sizes, int n_in,
                              void* d_out, int out_size, void* d_ws, size_t ws_size,
                              hipStream_t stream)
{
  const float* x   = (const float*)d_in[0];
  const float* Wx0 = (const float*)d_in[1];
  const float* bx0 = (const float*)d_in[2];
  const float* Wh0 = (const float*)d_in[3];
  const float* Wx1 = (const float*)d_in[4];
  const float* bx1 = (const float*)d_in[5];
  const float* Wh1 = (const float*)d_in[6];
  const float* Wfc = (const float*)d_in[7];
  const float* bfc = (const float*)d_in[8];

  uint8_t* ws = (uint8_t*)d_ws;
  uint32_t* prog0 = (uint32_t*)ws;                // 128 u32
  uint32_t* prog1 = (uint32_t*)(ws + 2048);       // 128 u32
  const size_t RINGB = (size_t)D_ * 4 * 16 * 512 * 8 * 4;  // 1 MB per ring (packed u32)
  uint32_t* ring0 = (uint32_t*)(ws + 4096);
  uint32_t* ring1 = (uint32_t*)(ws + 4096 + RINGB);
  float* h1f = (float*)(ws + 4096 + 2 * RINGB);   // 128 KB, fully rewritten each call

  // flags + rings must be zero every call (slot D-1 is the t=-1 state)
  (void)hipMemsetAsync(ws, 0, 4096 + 2 * RINGB, stream);

  hipLaunchKernelGGL(lstm_persist, dim3(G0_ + G1_), dim3(NTHR_), 0, stream,
                     x, Wx0, bx0, Wh0, Wx1, bx1, Wh1,
                     prog0, prog1, ring0, ring1, h1f);
  hipLaunchKernelGGL(fc_out, dim3(1), dim3(512), 0, stream,
                     h1f, Wfc, bfc, (float*)d_out);
}